// Round 1
// baseline (326.468 us; speedup 1.0000x reference)
//
#include <hip/hip_runtime.h>

typedef __bf16 bf16;
typedef __bf16 bf16x4 __attribute__((ext_vector_type(4)));
typedef __bf16 bf16x8 __attribute__((ext_vector_type(8)));
typedef float f32x4 __attribute__((ext_vector_type(4)));

#define DEV __device__ __forceinline__

typedef const __attribute__((address_space(1))) void gvoid_t;
typedef __attribute__((address_space(3))) void lvoid_t;

DEV void gload_lds16(const void* g, void* l) {
  __builtin_amdgcn_global_load_lds((gvoid_t*)g, (lvoid_t*)l, 16, 0, 0);
}

DEV f32x4 mfma16(bf16x8 a, bf16x8 b, f32x4 c) {
  return __builtin_amdgcn_mfma_f32_16x16x32_bf16(a, b, c, 0, 0, 0);
}

// ---------------------------------------------------------------------------
// Kernel A: f32 -> bf16 conversion, 4 elements/thread
// ---------------------------------------------------------------------------
__global__ __launch_bounds__(256) void cvt4_kernel(const float* __restrict__ src,
                                                   bf16* __restrict__ dst, int n4) {
  int i = blockIdx.x * 256 + threadIdx.x;
  if (i >= n4) return;
  float4 f = reinterpret_cast<const float4*>(src)[i];
  bf16x4 o;
  o[0] = (bf16)f.x; o[1] = (bf16)f.y; o[2] = (bf16)f.z; o[3] = (bf16)f.w;
  reinterpret_cast<bf16x4*>(dst)[i] = o;
}

// ---------------------------------------------------------------------------
// Kernel B: fused QKV projection GEMM.
// X: [4096][1024] bf16 (row-major, k-contig). W: [3072][1024] bf16 (rows =
// Wq|Wk|Wv, k-contig, torch Linear layout so y = x @ W^T). 128x128 tile,
// BK=64, 4 waves, 16x16x32 MFMA. Epilogue scatters to Q/K (bh,s,hd) and
// V transposed (bh,hd,s), adds bias.
// ---------------------------------------------------------------------------
__global__ __launch_bounds__(256) void gemm_qkv(
    const bf16* __restrict__ X, const bf16* __restrict__ W,
    const float* __restrict__ bq, const float* __restrict__ bk,
    const float* __restrict__ bv,
    bf16* __restrict__ Q, bf16* __restrict__ Kb, bf16* __restrict__ Vt) {
  __shared__ bf16 As[128 * 64];
  __shared__ bf16 Bs[128 * 64];
  const int t = threadIdx.x;
  const int lane = t & 63, w = t >> 6;
  const int wr = w >> 1, wc = w & 1;            // 2x2 wave grid, 64x64 each
  const int m0 = (blockIdx.x / 24) * 128;       // N blocks = 3072/128 = 24
  const int n0 = (blockIdx.x % 24) * 128;
  const int cl = lane & 15, g8 = (lane >> 4) * 8;

  f32x4 acc[4][4];
  for (int mi = 0; mi < 4; ++mi)
    for (int ni = 0; ni < 4; ++ni)
      for (int r = 0; r < 4; ++r) acc[mi][ni][r] = 0.0f;

  for (int k0 = 0; k0 < 1024; k0 += 64) {
#pragma unroll
    for (int i = 0; i < 4; ++i) {
      int c = i * 256 + t;                   // 16B chunk id, 1024 chunks/tile
      int row = c >> 3, col8 = (c & 7) * 8;  // 8 chunks per 64-elem row
      gload_lds16(X + (size_t)(m0 + row) * 1024 + k0 + col8, As + c * 8);
      gload_lds16(W + (size_t)(n0 + row) * 1024 + k0 + col8, Bs + c * 8);
    }
    __syncthreads();
#pragma unroll
    for (int kk = 0; kk < 64; kk += 32) {
      bf16x8 a[4], b[4];
#pragma unroll
      for (int mi = 0; mi < 4; ++mi)
        a[mi] = *(const bf16x8*)&As[(wr * 64 + mi * 16 + cl) * 64 + kk + g8];
#pragma unroll
      for (int ni = 0; ni < 4; ++ni)
        b[ni] = *(const bf16x8*)&Bs[(wc * 64 + ni * 16 + cl) * 64 + kk + g8];
#pragma unroll
      for (int mi = 0; mi < 4; ++mi)
#pragma unroll
        for (int ni = 0; ni < 4; ++ni)
          acc[mi][ni] = mfma16(a[mi], b[ni], acc[mi][ni]);
    }
    __syncthreads();
  }

  // Epilogue: C row = m0+wr*64+mi*16+(lane>>4)*4+r ; col = n0+wc*64+ni*16+cl
  const int rq = (lane >> 4) * 4;
#pragma unroll
  for (int mi = 0; mi < 4; ++mi) {
#pragma unroll
    for (int ni = 0; ni < 4; ++ni) {
      const int n = n0 + wc * 64 + ni * 16 + cl;
#pragma unroll
      for (int r = 0; r < 4; ++r) {
        const int m = m0 + wr * 64 + mi * 16 + rq + r;
        const int b = m >> 11, s = m & 2047;
        float v = acc[mi][ni][r];
        if (n < 1024) {
          v += bq[n];
          const int h = n >> 6, hd = n & 63;
          Q[(((size_t)(b * 16 + h)) * 2048 + s) * 64 + hd] = (bf16)v;
        } else if (n < 2048) {
          const int n2 = n - 1024;
          v += bk[n2];
          const int h = n2 >> 6, hd = n2 & 63;
          Kb[(((size_t)(b * 16 + h)) * 2048 + s) * 64 + hd] = (bf16)v;
        } else {
          const int n2 = n - 2048;
          v += bv[n2];
          const int h = n2 >> 6, hd = n2 & 63;
          Vt[(((size_t)(b * 16 + h)) * 64 + hd) * 2048 + s] = (bf16)v;
        }
      }
    }
  }
}

// ---------------------------------------------------------------------------
// Kernel C: causal flash attention. Block = 4 waves; wave owns 16 Q rows.
// KV tile = 32. Q [bh][s][64], K [bh][s][64], Vt [bh][64][s], out f32
// [b][s][h*64+hd]. scale = 1/8.
// ---------------------------------------------------------------------------
__global__ __launch_bounds__(256) void flash_attn(
    const bf16* __restrict__ Q, const bf16* __restrict__ K,
    const bf16* __restrict__ Vt, const int* __restrict__ amask,
    float* __restrict__ out) {
  __shared__ bf16 pl[4][16][32];
  const int t = threadIdx.x, lane = t & 63, w = t >> 6;
  const int bh = blockIdx.x >> 5;   // 0..31
  const int qt = blockIdx.x & 31;   // 0..31 (64-row q tiles)
  const int b = bh >> 4, h = bh & 15;
  const int q0 = qt * 64 + w * 16;
  const int cl = lane & 15, g8 = (lane >> 4) * 8, rq = (lane >> 4) * 4;

  const bf16* Qp = Q + (size_t)bh * 2048 * 64;
  const bf16* Kp = K + (size_t)bh * 2048 * 64;
  const bf16* Vp = Vt + (size_t)bh * 64 * 2048;

  const bf16x8 qf0 = *(const bf16x8*)&Qp[(size_t)(q0 + cl) * 64 + g8];
  const bf16x8 qf1 = *(const bf16x8*)&Qp[(size_t)(q0 + cl) * 64 + 32 + g8];

  f32x4 o[4];
  for (int c = 0; c < 4; ++c)
    for (int r = 0; r < 4; ++r) o[c][r] = 0.0f;
  float mrun[4] = {-1e30f, -1e30f, -1e30f, -1e30f};
  float lrun[4] = {0.f, 0.f, 0.f, 0.f};

  const int ntiles = (q0 + 16 + 31) / 32;
  for (int kt = 0; kt < ntiles; ++kt) {
    const int kv0 = kt * 32;
    // --- QK^T: S[16q x 32kv]
    f32x4 s[2];
#pragma unroll
    for (int sub = 0; sub < 2; ++sub) {
      const int krow = kv0 + sub * 16 + cl;
      bf16x8 kf0 = *(const bf16x8*)&Kp[(size_t)krow * 64 + g8];
      bf16x8 kf1 = *(const bf16x8*)&Kp[(size_t)krow * 64 + 32 + g8];
      f32x4 z;
      z[0] = z[1] = z[2] = z[3] = 0.0f;
      z = mfma16(qf0, kf0, z);
      z = mfma16(qf1, kf1, z);
      s[sub] = z;
    }
    // --- mask + scale
    const int kva = kv0 + cl, kvb = kv0 + 16 + cl;
    const bool pada = amask[b * 2048 + kva] != 0;
    const bool padb = amask[b * 2048 + kvb] != 0;
    float sv[2][4], pm[4];
#pragma unroll
    for (int r = 0; r < 4; ++r) {
      const int qg = q0 + rq + r;
      float v0 = (kva > qg || pada) ? -1e30f : s[0][r] * 0.125f;
      float v1 = (kvb > qg || padb) ? -1e30f : s[1][r] * 0.125f;
      sv[0][r] = v0; sv[1][r] = v1;
      pm[r] = fmaxf(v0, v1);
    }
    // --- row max across the 16-lane group
#pragma unroll
    for (int r = 0; r < 4; ++r)
      for (int msk = 1; msk < 16; msk <<= 1)
        pm[r] = fmaxf(pm[r], __shfl_xor(pm[r], msk, 64));
    // --- online softmax update
    float fr[4];
#pragma unroll
    for (int r = 0; r < 4; ++r) {
      const float mn = fmaxf(mrun[r], pm[r]);
      fr[r] = __expf(mrun[r] - mn);
      mrun[r] = mn;
      const float p0 = __expf(sv[0][r] - mn);
      const float p1 = __expf(sv[1][r] - mn);
      float rs = p0 + p1;
      for (int msk = 1; msk < 16; msk <<= 1) rs += __shfl_xor(rs, msk, 64);
      lrun[r] = lrun[r] * fr[r] + rs;
      pl[w][rq + r][cl] = (bf16)p0;
      pl[w][rq + r][16 + cl] = (bf16)p1;
    }
#pragma unroll
    for (int c = 0; c < 4; ++c)
#pragma unroll
      for (int r = 0; r < 4; ++r) o[c][r] *= fr[r];
    // --- PV: O[16q x 64hd] += P[16x32] @ V[32 x 64]
    const bf16x8 pa = *(const bf16x8*)&pl[w][cl][g8];
#pragma unroll
    for (int c = 0; c < 4; ++c) {
      bf16x8 vf = *(const bf16x8*)&Vp[(size_t)(c * 16 + cl) * 2048 + kv0 + g8];
      o[c] = mfma16(pa, vf, o[c]);
    }
  }

  // --- epilogue: out[b][q][h*64 + c*16 + cl]
#pragma unroll
  for (int c = 0; c < 4; ++c) {
#pragma unroll
    for (int r = 0; r < 4; ++r) {
      const int qg = q0 + rq + r;
      out[((size_t)b * 2048 + qg) * 1024 + h * 64 + c * 16 + cl] =
          o[c][r] / lrun[r];
    }
  }
}

// ---------------------------------------------------------------------------
extern "C" void kernel_launch(void* const* d_in, const int* in_sizes, int n_in,
                              void* d_out, int out_size, void* d_ws,
                              size_t ws_size, hipStream_t stream) {
  const float* hs = (const float*)d_in[0];
  const int* amask = (const int*)d_in[1];
  const float* Wq = (const float*)d_in[2];
  const float* bq = (const float*)d_in[3];
  const float* Wk = (const float*)d_in[4];
  const float* bk = (const float*)d_in[5];
  const float* Wv = (const float*)d_in[6];
  const float* bv = (const float*)d_in[7];
  float* out = (float*)d_out;

  char* ws = (char*)d_ws;
  bf16* Xb = (bf16*)ws;                               // 8 MB: [4096][1024]
  bf16* Wb = (bf16*)(ws + 8ull * 1024 * 1024);        // 6 MB: [3072][1024]
  bf16* Qb = (bf16*)(ws + 14ull * 1024 * 1024);       // 8 MB: [32][2048][64]
  bf16* Kb = (bf16*)(ws + 22ull * 1024 * 1024);       // 8 MB: [32][2048][64]
  bf16* Vtb = (bf16*)(ws + 30ull * 1024 * 1024);      // 8 MB: [32][64][2048]

  cvt4_kernel<<<4096, 256, 0, stream>>>(hs, Xb, 1048576);
  cvt4_kernel<<<1024, 256, 0, stream>>>(Wq, Wb, 262144);
  cvt4_kernel<<<1024, 256, 0, stream>>>(Wk, Wb + 1024 * 1024, 262144);
  cvt4_kernel<<<1024, 256, 0, stream>>>(Wv, Wb + 2 * 1024 * 1024, 262144);

  gemm_qkv<<<768, 256, 0, stream>>>(Xb, Wb, bq, bk, bv, Qb, Kb, Vtb);

  flash_attn<<<1024, 256, 0, stream>>>(Qb, Kb, Vtb, amask, out);
}

// Round 2
// 195.235 us; speedup vs baseline: 1.6722x; 1.6722x over previous
//
#include <hip/hip_runtime.h>

typedef __bf16 bf16;
typedef __bf16 bf16x4 __attribute__((ext_vector_type(4)));
typedef __bf16 bf16x8 __attribute__((ext_vector_type(8)));
typedef float f32x4 __attribute__((ext_vector_type(4)));

#define DEV __device__ __forceinline__

typedef const __attribute__((address_space(1))) void gvoid_t;
typedef __attribute__((address_space(3))) void lvoid_t;

DEV void gload_lds16(const void* g, void* l) {
  __builtin_amdgcn_global_load_lds((gvoid_t*)g, (lvoid_t*)l, 16, 0, 0);
}

DEV f32x4 mfma16(bf16x8 a, bf16x8 b, f32x4 c) {
  return __builtin_amdgcn_mfma_f32_16x16x32_bf16(a, b, c, 0, 0, 0);
}

// ---------------------------------------------------------------------------
// Kernel A: f32 -> bf16 conversion, 4 elements/thread
// ---------------------------------------------------------------------------
__global__ __launch_bounds__(256) void cvt4_kernel(const float* __restrict__ src,
                                                   bf16* __restrict__ dst, int n4) {
  int i = blockIdx.x * 256 + threadIdx.x;
  if (i >= n4) return;
  float4 f = reinterpret_cast<const float4*>(src)[i];
  bf16x4 o;
  o[0] = (bf16)f.x; o[1] = (bf16)f.y; o[2] = (bf16)f.z; o[3] = (bf16)f.w;
  reinterpret_cast<bf16x4*>(dst)[i] = o;
}

// ---------------------------------------------------------------------------
// Kernel B: fused QKV projection GEMM (unchanged from round 1).
// ---------------------------------------------------------------------------
__global__ __launch_bounds__(256) void gemm_qkv(
    const bf16* __restrict__ X, const bf16* __restrict__ W,
    const float* __restrict__ bq, const float* __restrict__ bk,
    const float* __restrict__ bv,
    bf16* __restrict__ Q, bf16* __restrict__ Kb, bf16* __restrict__ Vt) {
  __shared__ bf16 As[128 * 64];
  __shared__ bf16 Bs[128 * 64];
  const int t = threadIdx.x;
  const int lane = t & 63, w = t >> 6;
  const int wr = w >> 1, wc = w & 1;
  const int m0 = (blockIdx.x / 24) * 128;
  const int n0 = (blockIdx.x % 24) * 128;
  const int cl = lane & 15, g8 = (lane >> 4) * 8;

  f32x4 acc[4][4];
  for (int mi = 0; mi < 4; ++mi)
    for (int ni = 0; ni < 4; ++ni)
      for (int r = 0; r < 4; ++r) acc[mi][ni][r] = 0.0f;

  for (int k0 = 0; k0 < 1024; k0 += 64) {
#pragma unroll
    for (int i = 0; i < 4; ++i) {
      int c = i * 256 + t;
      int row = c >> 3, col8 = (c & 7) * 8;
      gload_lds16(X + (size_t)(m0 + row) * 1024 + k0 + col8, As + c * 8);
      gload_lds16(W + (size_t)(n0 + row) * 1024 + k0 + col8, Bs + c * 8);
    }
    __syncthreads();
#pragma unroll
    for (int kk = 0; kk < 64; kk += 32) {
      bf16x8 a[4], b[4];
#pragma unroll
      for (int mi = 0; mi < 4; ++mi)
        a[mi] = *(const bf16x8*)&As[(wr * 64 + mi * 16 + cl) * 64 + kk + g8];
#pragma unroll
      for (int ni = 0; ni < 4; ++ni)
        b[ni] = *(const bf16x8*)&Bs[(wc * 64 + ni * 16 + cl) * 64 + kk + g8];
#pragma unroll
      for (int mi = 0; mi < 4; ++mi)
#pragma unroll
        for (int ni = 0; ni < 4; ++ni)
          acc[mi][ni] = mfma16(a[mi], b[ni], acc[mi][ni]);
    }
    __syncthreads();
  }

  const int rq = (lane >> 4) * 4;
#pragma unroll
  for (int mi = 0; mi < 4; ++mi) {
#pragma unroll
    for (int ni = 0; ni < 4; ++ni) {
      const int n = n0 + wc * 64 + ni * 16 + cl;
#pragma unroll
      for (int r = 0; r < 4; ++r) {
        const int m = m0 + wr * 64 + mi * 16 + rq + r;
        const int b = m >> 11, s = m & 2047;
        float v = acc[mi][ni][r];
        if (n < 1024) {
          v += bq[n];
          const int h = n >> 6, hd = n & 63;
          Q[(((size_t)(b * 16 + h)) * 2048 + s) * 64 + hd] = (bf16)v;
        } else if (n < 2048) {
          const int n2 = n - 1024;
          v += bk[n2];
          const int h = n2 >> 6, hd = n2 & 63;
          Kb[(((size_t)(b * 16 + h)) * 2048 + s) * 64 + hd] = (bf16)v;
        } else {
          const int n2 = n - 2048;
          v += bv[n2];
          const int h = n2 >> 6, hd = n2 & 63;
          Vt[(((size_t)(b * 16 + h)) * 64 + hd) * 2048 + s] = (bf16)v;
        }
      }
    }
  }
}

// ---------------------------------------------------------------------------
// Kernel C: causal flash attention, v2.
// Block = 4 waves, QBLK=128 (32 rows/wave), KVBLK=64.
// K tile [64 kv][64 k] and Vt tile [64 hd][64 kv] staged in LDS
// (double-buffered, XOR-swizzled via pre-swizzled global source).
// Softmax: wave-scalar running max (6 shfl/tile); row-sum via a 5th MFMA
// output column (ones B-fragment). P through per-wave swizzled LDS.
// ---------------------------------------------------------------------------
__global__ __launch_bounds__(256, 3) void flash_attn(
    const bf16* __restrict__ Q, const bf16* __restrict__ K,
    const bf16* __restrict__ Vt, const int* __restrict__ amask,
    float* __restrict__ out) {
  __shared__ bf16 Ks[2][64 * 64];
  __shared__ bf16 Vs[2][64 * 64];
  __shared__ bf16 Ps[4][32 * 64];
  const int t = threadIdx.x, lane = t & 63, w = t >> 6;
  const int bh = blockIdx.x & 31;
  const int qb = 15 - (blockIdx.x >> 5);  // heavy q-blocks dispatch first
  const int b = bh >> 4, h = bh & 15;
  const int q0w = qb * 128 + w * 32;
  const int cl = lane & 15, g8 = (lane >> 4) * 8, rq = (lane >> 4) * 4;

  const bf16* Qp = Q + (size_t)bh * 2048 * 64;
  const bf16* Kp = K + (size_t)bh * 2048 * 64;
  const bf16* Vp = Vt + (size_t)bh * 64 * 2048;

  // Q fragments in registers: rows q0w + mi*16 + cl, k-slices ks*32+g8
  bf16x8 qf[2][2];
#pragma unroll
  for (int mi = 0; mi < 2; ++mi)
#pragma unroll
    for (int ks = 0; ks < 2; ++ks)
      qf[mi][ks] =
          *(const bf16x8*)&Qp[(size_t)(q0w + mi * 16 + cl) * 64 + ks * 32 + g8];

  // ones B-fragment: B[0][k] = 1, rows 1..15 zero -> col 0 of D = rowsum
  bf16x8 ones;
#pragma unroll
  for (int j = 0; j < 8; ++j) ones[j] = (cl == 0) ? (bf16)1.0f : (bf16)0.0f;

  f32x4 o[2][5];  // [mi][0..3]=hd frags, [4]=rowsum col
#pragma unroll
  for (int mi = 0; mi < 2; ++mi)
#pragma unroll
    for (int nc = 0; nc < 5; ++nc)
#pragma unroll
      for (int r = 0; r < 4; ++r) o[mi][nc][r] = 0.0f;
  float mrun = -1e30f;

  const int ntiles = 2 * qb + 2;

  // prologue: stage tile 0 into buf 0
#pragma unroll
  for (int p = 0; p < 2; ++p) {
    int c = p * 256 + t, row = c >> 3, sl = (c & 7) ^ (row & 7);
    gload_lds16(Kp + (size_t)row * 64 + sl * 8, &Ks[0][c * 8]);
    gload_lds16(Vp + (size_t)row * 2048 + sl * 8, &Vs[0][c * 8]);
  }
  __syncthreads();

  int buf = 0;
  for (int kt = 0; kt < ntiles; ++kt) {
    const int kv0 = kt * 64;
    // prefetch next tile into buf^1
    if (kt + 1 < ntiles) {
      const int nv0 = kv0 + 64;
#pragma unroll
      for (int p = 0; p < 2; ++p) {
        int c = p * 256 + t, row = c >> 3, sl = (c & 7) ^ (row & 7);
        gload_lds16(Kp + (size_t)(nv0 + row) * 64 + sl * 8, &Ks[buf ^ 1][c * 8]);
        gload_lds16(Vp + (size_t)row * 2048 + nv0 + sl * 8, &Vs[buf ^ 1][c * 8]);
      }
    }
    if (kv0 <= q0w + 31) {  // wave-uniform: tile intersects this wave's rows
      const int av = amask[b * 2048 + kv0 + lane];
      const unsigned long long padb = __ballot(av != 0);
      // ---- QK^T: S[32 x 64]
      f32x4 sacc[2][4];
#pragma unroll
      for (int mi = 0; mi < 2; ++mi)
#pragma unroll
        for (int nj = 0; nj < 4; ++nj)
#pragma unroll
          for (int r = 0; r < 4; ++r) sacc[mi][nj][r] = 0.0f;
#pragma unroll
      for (int ks = 0; ks < 2; ++ks) {
#pragma unroll
        for (int nj = 0; nj < 4; ++nj) {
          const int row = nj * 16 + cl;
          const bf16x8 kf = *(const bf16x8*)&Ks[buf][row * 64 +
                                ((ks * 32 + g8) ^ ((row & 7) << 3))];
          sacc[0][nj] = mfma16(qf[0][ks], kf, sacc[0][nj]);
          sacc[1][nj] = mfma16(qf[1][ks], kf, sacc[1][nj]);
        }
      }
      // ---- scale + mask
      const bool anymask = (kv0 + 63 > q0w) || (padb != 0ull);
      float sv[2][4][4];
#pragma unroll
      for (int mi = 0; mi < 2; ++mi)
#pragma unroll
        for (int nj = 0; nj < 4; ++nj)
#pragma unroll
          for (int r = 0; r < 4; ++r) {
            float x = sacc[mi][nj][r] * 0.125f;
            if (anymask) {
              const int col = kv0 + nj * 16 + cl;
              const int row = q0w + mi * 16 + rq + r;
              const bool bad = (col > row) || ((padb >> (nj * 16 + cl)) & 1ull);
              x = bad ? -1e30f : x;
            }
            sv[mi][nj][r] = x;
          }
      // ---- wave-scalar max
      float tm = -1e30f;
#pragma unroll
      for (int mi = 0; mi < 2; ++mi)
#pragma unroll
        for (int nj = 0; nj < 4; ++nj)
#pragma unroll
          for (int r = 0; r < 4; ++r) tm = fmaxf(tm, sv[mi][nj][r]);
#pragma unroll
      for (int d = 1; d < 64; d <<= 1) tm = fmaxf(tm, __shfl_xor(tm, d, 64));
      const float mn = fmaxf(mrun, tm);
      const float fr = __expf(mrun - mn);
      mrun = mn;
#pragma unroll
      for (int mi = 0; mi < 2; ++mi)
#pragma unroll
        for (int nc = 0; nc < 5; ++nc)
#pragma unroll
          for (int r = 0; r < 4; ++r) o[mi][nc][r] *= fr;
      // ---- exp + write P (swizzled)
#pragma unroll
      for (int mi = 0; mi < 2; ++mi)
#pragma unroll
        for (int nj = 0; nj < 4; ++nj)
#pragma unroll
          for (int r = 0; r < 4; ++r) {
            const float p = __expf(sv[mi][nj][r] - mn);
            const int row = mi * 16 + rq + r;
            Ps[w][row * 64 + ((nj * 16 + cl) ^ ((row & 7) << 3))] = (bf16)p;
          }
      // ---- PV: O[32 x 64] += P[32 x 64] @ V[64 x 64]
      bf16x8 pa[2][2];
#pragma unroll
      for (int mi = 0; mi < 2; ++mi)
#pragma unroll
        for (int ks = 0; ks < 2; ++ks) {
          const int row = mi * 16 + cl;
          pa[mi][ks] = *(const bf16x8*)&Ps[w][row * 64 +
                            ((ks * 32 + g8) ^ ((row & 7) << 3))];
        }
#pragma unroll
      for (int ks = 0; ks < 2; ++ks) {
#pragma unroll
        for (int nc = 0; nc < 4; ++nc) {
          const int row = nc * 16 + cl;
          const bf16x8 vf = *(const bf16x8*)&Vs[buf][row * 64 +
                                ((ks * 32 + g8) ^ ((row & 7) << 3))];
          o[0][nc] = mfma16(pa[0][ks], vf, o[0][nc]);
          o[1][nc] = mfma16(pa[1][ks], vf, o[1][nc]);
        }
        o[0][4] = mfma16(pa[0][ks], ones, o[0][4]);
        o[1][4] = mfma16(pa[1][ks], ones, o[1][4]);
      }
    }
    __syncthreads();
    buf ^= 1;
  }

  // ---- epilogue: normalize by rowsum (col 0 of o[mi][4], lanes cl==0)
#pragma unroll
  for (int mi = 0; mi < 2; ++mi)
#pragma unroll
    for (int r = 0; r < 4; ++r) {
      const float l = __shfl(o[mi][4][r], lane & 48, 64);
      const float inv = 1.0f / l;
      const int qg = q0w + mi * 16 + rq + r;
#pragma unroll
      for (int nc = 0; nc < 4; ++nc)
        out[((size_t)b * 2048 + qg) * 1024 + h * 64 + nc * 16 + cl] =
            o[mi][nc][r] * inv;
    }
}

// ---------------------------------------------------------------------------
extern "C" void kernel_launch(void* const* d_in, const int* in_sizes, int n_in,
                              void* d_out, int out_size, void* d_ws,
                              size_t ws_size, hipStream_t stream) {
  const float* hs = (const float*)d_in[0];
  const int* amask = (const int*)d_in[1];
  const float* Wq = (const float*)d_in[2];
  const float* bq = (const float*)d_in[3];
  const float* Wk = (const float*)d_in[4];
  const float* bk = (const float*)d_in[5];
  const float* Wv = (const float*)d_in[6];
  const float* bv = (const float*)d_in[7];
  float* out = (float*)d_out;

  char* ws = (char*)d_ws;
  bf16* Xb = (bf16*)ws;                               // 8 MB: [4096][1024]
  bf16* Wb = (bf16*)(ws + 8ull * 1024 * 1024);        // 6 MB: [3072][1024]
  bf16* Qb = (bf16*)(ws + 14ull * 1024 * 1024);       // 8 MB: [32][2048][64]
  bf16* Kb = (bf16*)(ws + 22ull * 1024 * 1024);       // 8 MB: [32][2048][64]
  bf16* Vtb = (bf16*)(ws + 30ull * 1024 * 1024);      // 8 MB: [32][64][2048]

  cvt4_kernel<<<4096, 256, 0, stream>>>(hs, Xb, 1048576);
  cvt4_kernel<<<1024, 256, 0, stream>>>(Wq, Wb, 262144);
  cvt4_kernel<<<1024, 256, 0, stream>>>(Wk, Wb + 1024 * 1024, 262144);
  cvt4_kernel<<<1024, 256, 0, stream>>>(Wv, Wb + 2 * 1024 * 1024, 262144);

  gemm_qkv<<<768, 256, 0, stream>>>(Xb, Wb, bq, bk, bv, Qb, Kb, Vtb);

  flash_attn<<<512, 256, 0, stream>>>(Qb, Kb, Vtb, amask, out);
}